// Round 12
// baseline (236.556 us; speedup 1.0000x reference)
//
#include <hip/hip_runtime.h>

#define B_ 32
#define C_ 512
#define HW_ 4096
#define N_ 80

typedef __bf16 bf16x8 __attribute__((ext_vector_type(8)));
typedef __bf16 bf16x4 __attribute__((ext_vector_type(4)));
typedef float f32x4 __attribute__((ext_vector_type(4)));
typedef unsigned short u16x8 __attribute__((ext_vector_type(8)));

__device__ __forceinline__ void gload_lds16(const void* g, void* l) {
  __builtin_amdgcn_global_load_lds((const __attribute__((address_space(1))) void*)g,
                                   (__attribute__((address_space(3))) void*)l, 16, 0, 0);
}

#define VMCNT(n) asm volatile("s_waitcnt vmcnt(" #n ")" ::: "memory")
#define LGKM0() asm volatile("s_waitcnt lgkmcnt(0)" ::: "memory")
#define SBAR() asm volatile("s_barrier" ::: "memory")
#define MFMA(a, b, c) __builtin_amdgcn_mfma_f32_16x16x32_bf16(a, b, c, 0, 0, 0)

// ---------------------------------------------------------------------------
// K0: refragment W -> Wfrag bf16 (MFMA B-operand unit layout) AND zero denom.
// ---------------------------------------------------------------------------
__global__ __launch_bounds__(256) void k0_wfrag(const float* __restrict__ W,
                                                __bf16* __restrict__ Wfrag,
                                                float* __restrict__ denom) {
  const int t = blockIdx.x * 256 + threadIdx.x;
  if (t < B_ * N_) denom[t] = 0.f;
  if (t >= 16 * 5 * 64) return;
  const int cs = t / 320, rem = t % 320;
  const int nf = rem >> 6, lane = rem & 63;
  const int n = nf * 16 + (lane & 15);
  const int c = cs * 32 + (lane >> 4) * 8;
  const float* wp = W + (size_t)n * C_ + c;
  bf16x8 v;
#pragma unroll
  for (int i = 0; i < 8; ++i) v[i] = (__bf16)wp[i];
  *(bf16x8*)(Wfrag + (size_t)t * 8) = v;
}

// ---------------------------------------------------------------------------
// KF: fused (R10 structure, VGPR-cap fix). Block = (b, hs in [0,8)). 8 waves.
// Per 64-h chunk hc:
//   8 cc-iters: [vmcnt(2); bar; wf-prefetch(+1); stage(+2); logits-MFMA;
//                convert ftile->pvbuf bf16 (XOR swz)]
//   phaseB: exp(lacc)->elds (XOR swz) + reg denom partials
//   phaseC: PV MFMA pvbuf x elds -> persistent acc[4][5]
// LDS: ftile 3x16KB + pvbuf 64KB + elds 10KB = 122 KB -> 1 block/CU.
// __launch_bounds__(512) (NOT ,2): ~200 VGPR live set, no scratch spill.
// ---------------------------------------------------------------------------
#define STAGE(S)                                                                  \
  do {                                                                            \
    const int slot_ = (S) % 3;                                                    \
    const int hc_ = (S) >> 3, cc_ = (S) & 7;                                      \
    const float* g0_ =                                                            \
        fb + (size_t)(cc_ * 64 + srow) * HW_ + hbase + hc_ * 64 + scol4;          \
    gload_lds16(g0_, (char*)ftile + slot_ * 16384 + w * 1024);                    \
    gload_lds16(g0_ + (size_t)32 * HW_,                                           \
                (char*)ftile + slot_ * 16384 + 8192 + w * 1024);                  \
  } while (0)

#define WFLOAD(DST, CC)                                                           \
  do {                                                                            \
    _Pragma("unroll") for (int ks_ = 0; ks_ < 2; ++ks_)                           \
    _Pragma("unroll") for (int nf_ = 0; nf_ < 3; ++nf_)                           \
      if (nf_ < nfcnt)                                                            \
        DST[ks_][nf_] = *(const u16x8*)(Wfrag +                                   \
            ((size_t)(((CC)*2 + ks_) * 5 + nfbase + nf_) * 64 + lane) * 8);       \
  } while (0)

#define LOGITS(S, WU)                                                             \
  do {                                                                            \
    const float* tb_ = (const float*)((char*)ftile + ((S) % 3) * 16384);          \
    _Pragma("unroll") for (int ks_ = 0; ks_ < 2; ++ks_) {                         \
      bf16x8 af_;                                                                 \
      _Pragma("unroll") for (int i_ = 0; i_ < 8; ++i_)                            \
        af_[i_] = (__bf16)tb_[(ks_ * 32 + quad * 8 + i_) * 64 + hq * 16 + l16];   \
      _Pragma("unroll") for (int nf_ = 0; nf_ < 3; ++nf_)                         \
        if (nf_ < nfcnt) {                                                        \
          const bf16x8 bf_ = __builtin_bit_cast(bf16x8, WU[ks_][nf_]);            \
          lacc[nf_] = MFMA(af_, bf_, lacc[nf_]);                                  \
        }                                                                         \
    }                                                                             \
  } while (0)

#define CONVERT(S, CC)                                                            \
  do {                                                                            \
    const float* sb_ = (const float*)((char*)ftile + ((S) % 3) * 16384);          \
    const int r_ = tid >> 3, p_ = tid & 7;                                        \
    const f32x4 v0_ = *(const f32x4*)(sb_ + r_ * 64 + p_ * 8);                    \
    const f32x4 v1_ = *(const f32x4*)(sb_ + r_ * 64 + p_ * 8 + 4);                \
    bf16x8 o_;                                                                    \
    o_[0] = (__bf16)v0_[0]; o_[1] = (__bf16)v0_[1];                               \
    o_[2] = (__bf16)v0_[2]; o_[3] = (__bf16)v0_[3];                               \
    o_[4] = (__bf16)v1_[0]; o_[5] = (__bf16)v1_[1];                               \
    o_[6] = (__bf16)v1_[2]; o_[7] = (__bf16)v1_[3];                               \
    *(bf16x8*)&pvbuf[((CC)*64 + r_) * 64 + (p_ ^ (r_ & 7)) * 8] = o_;             \
  } while (0)

#define ITER(HC, CC, WU, WL)                                                      \
  do {                                                                            \
    VMCNT(2);                                                                     \
    SBAR();                                                                       \
    WFLOAD(WL, ((CC) + 1) & 7);                                                   \
    if ((HC)*8 + (CC) + 2 < 64) STAGE((HC)*8 + (CC) + 2);                         \
    LOGITS((HC)*8 + (CC), WU);                                                    \
    CONVERT((HC)*8 + (CC), CC);                                                   \
  } while (0)

#define PHASEB()                                                                  \
  do {                                                                            \
    _Pragma("unroll") for (int nf_ = 0; nf_ < 3; ++nf_) if (nf_ < nfcnt) {        \
      const float e0_ = __expf(lacc[nf_][0]);                                     \
      const float e1_ = __expf(lacc[nf_][1]);                                     \
      const float e2_ = __expf(lacc[nf_][2]);                                     \
      const float e3_ = __expf(lacc[nf_][3]);                                     \
      dsum[nf_] += e0_ + e1_ + e2_ + e3_;                                         \
      bf16x4 pk_;                                                                 \
      pk_[0] = (__bf16)e0_; pk_[1] = (__bf16)e1_;                                 \
      pk_[2] = (__bf16)e2_; pk_[3] = (__bf16)e3_;                                 \
      const int n_ = (nfbase + nf_) * 16 + l16;                                   \
      const int pp_ = (hq * 2 + (quad >> 1)) ^ (l16 & 7);                         \
      *(bf16x4*)&elds[n_ * 64 + pp_ * 8 + (quad & 1) * 4] = pk_;                  \
      lacc[nf_] = zero;                                                           \
    }                                                                             \
  } while (0)

#define PHASEC()                                                                  \
  do {                                                                            \
    _Pragma("unroll") for (int ks_ = 0; ks_ < 2; ++ks_) {                         \
      bf16x8 a_[4];                                                               \
      _Pragma("unroll") for (int cf_ = 0; cf_ < 4; ++cf_) {                       \
        const int c_ = w * 64 + cf_ * 16 + l16;                                   \
        a_[cf_] = *(const bf16x8*)&pvbuf[c_ * 64 + ((ks_ * 4 + quad) ^ (l16 & 7)) * 8]; \
      }                                                                           \
      _Pragma("unroll") for (int nf_ = 0; nf_ < 5; ++nf_) {                       \
        const int n_ = nf_ * 16 + l16;                                            \
        const bf16x8 b_ =                                                         \
            *(const bf16x8*)&elds[n_ * 64 + ((ks_ * 4 + quad) ^ (l16 & 7)) * 8];  \
        _Pragma("unroll") for (int cf_ = 0; cf_ < 4; ++cf_)                       \
          acc[cf_][nf_] = MFMA(a_[cf_], b_, acc[cf_][nf_]);                       \
      }                                                                           \
    }                                                                             \
  } while (0)

__global__ __launch_bounds__(512) void kf_fused(const float* __restrict__ feats,
                                                const __bf16* __restrict__ Wfrag,
                                                float* __restrict__ part,
                                                float* __restrict__ denom) {
  __shared__ float ftile[3][64 * 64];   // 48 KB staging (linear)
  __shared__ __bf16 pvbuf[512 * 64];    // 64 KB feats bf16, XOR p^(c&7)
  __shared__ __bf16 elds[80 * 64];      // 10 KB E bf16, XOR p^(n&7)

  const int tid = threadIdx.x;
  const int lane = tid & 63, w = tid >> 6;
  const int quad = lane >> 4, l16 = lane & 15;
  const int hq = w >> 1, ng = w & 1;
  const int nfbase = ng ? 3 : 0, nfcnt = ng ? 2 : 3;
  const int bid = blockIdx.x;
  const int b = bid & 31, hs = bid >> 5;
  const float* fb = feats + (size_t)b * (C_ * HW_);
  const int hbase = hs * 512;
  const int srow = tid >> 4;          // staging c-row (and +32)
  const int scol4 = (tid & 15) * 4;   // staging h-offset (floats)

  const f32x4 zero = {0.f, 0.f, 0.f, 0.f};
  f32x4 acc[4][5];
#pragma unroll
  for (int cf = 0; cf < 4; ++cf)
#pragma unroll
    for (int nf = 0; nf < 5; ++nf) acc[cf][nf] = zero;
  f32x4 lacc[3];
#pragma unroll
  for (int i = 0; i < 3; ++i) lacc[i] = zero;
  float dsum[3] = {0.f, 0.f, 0.f};

  u16x8 wfA[2][3], wfB[2][3];
  // prologue FIFO: wf0 BEFORE stages so vmcnt(2) covers it at iter 0
  WFLOAD(wfA, 0);
  STAGE(0);
  STAGE(1);

  for (int hc = 0; hc < 8; ++hc) {
    ITER(hc, 0, wfA, wfB);
    ITER(hc, 1, wfB, wfA);
    ITER(hc, 2, wfA, wfB);
    ITER(hc, 3, wfB, wfA);
    ITER(hc, 4, wfA, wfB);
    ITER(hc, 5, wfB, wfA);
    ITER(hc, 6, wfA, wfB);
    if (hc < 7) {
      ITER(hc, 7, wfB, wfA);
    } else {
      VMCNT(0);
      SBAR();
      LOGITS(63, wfB);
      CONVERT(63, 7);
    }
    LGKM0();
    SBAR();   // conversions (all cc) + logits done -> phaseB may write elds
    PHASEB();
    LGKM0();
    SBAR();   // elds ready -> PV
    PHASEC();
    // next iteration's vmcnt+barrier separates PV reads from next conversions
  }

  // epilogue: partial store + denom atomics (once per block)
  float* pb = part + (size_t)hs * (B_ * N_ * C_) + (size_t)b * (N_ * C_);
#pragma unroll
  for (int cf = 0; cf < 4; ++cf)
#pragma unroll
    for (int nf = 0; nf < 5; ++nf) {
      const int n = nf * 16 + l16;
      float4 v;
      v.x = acc[cf][nf][0]; v.y = acc[cf][nf][1];
      v.z = acc[cf][nf][2]; v.w = acc[cf][nf][3];
      *(float4*)(pb + (size_t)n * C_ + w * 64 + cf * 16 + quad * 4) = v;
    }
#pragma unroll
  for (int nf = 0; nf < 3; ++nf)
    if (nf < nfcnt) {
      float s = dsum[nf];
      s += __shfl_xor(s, 16);
      s += __shfl_xor(s, 32);
      if (lane < 16) atomicAdd(denom + b * N_ + (nfbase + nf) * 16 + lane, s);
    }
}

// ---------------------------------------------------------------------------
// K4: out = (sum_hs part[hs]) / denom[b][n]
// ---------------------------------------------------------------------------
__global__ __launch_bounds__(256) void k4_reduce(const float* __restrict__ part,
                                                 const float* __restrict__ denom,
                                                 float* __restrict__ out) {
  const size_t i = ((size_t)blockIdx.x * 256 + threadIdx.x) * 4;
  if (i >= (size_t)B_ * N_ * C_) return;
  float4 s = *(const float4*)(part + i);
#pragma unroll
  for (int hz = 1; hz < 8; ++hz) {
    const float4 v = *(const float4*)(part + (size_t)hz * (B_ * N_ * C_) + i);
    s.x += v.x; s.y += v.y; s.z += v.z; s.w += v.w;
  }
  const float r = 1.0f / denom[i >> 9];
  s.x *= r; s.y *= r; s.z *= r; s.w *= r;
  *(float4*)(out + i) = s;
}

extern "C" void kernel_launch(void* const* d_in, const int* in_sizes, int n_in,
                              void* d_out, int out_size, void* d_ws, size_t ws_size,
                              hipStream_t stream) {
  (void)in_sizes; (void)n_in; (void)out_size; (void)ws_size;
  const float* feats = (const float*)d_in[0];
  const float* Wm = (const float*)d_in[1];
  float* out = (float*)d_out;

  __bf16* Wfrag = (__bf16*)d_ws;                       // 80 KB
  float* part = (float*)((char*)d_ws + 81920);         // 8 x 5.24 MB = 42 MB
  float* denom = part + (size_t)8 * B_ * N_ * C_;      // 10 KB

  hipLaunchKernelGGL(k0_wfrag, dim3(20), dim3(256), 0, stream, Wm, Wfrag, denom);
  hipLaunchKernelGGL(kf_fused, dim3(256), dim3(512), 0, stream, feats, Wfrag, part, denom);
  const int n4 = (B_ * N_ * C_) / 4;
  hipLaunchKernelGGL(k4_reduce, dim3(n4 / 256), dim3(256), 0, stream, part, denom, out);
}